// Round 6
// baseline (653.886 us; speedup 1.0000x reference)
//
#include <hip/hip_runtime.h>
#include <hip/hip_fp16.h>
#include <math.h>

#define SCALE 0.4082482904638631f   // 1/sqrt(6)

#define BATCH 8
#define NPIX  65536

// ---------------- workspace layout ----------------
#define QKV_H_SIZE ((size_t)BATCH*144*NPIX)        // halves
#define VP_H_SIZE  ((size_t)BATCH*48*NPIX)         // halves
#define F_BYTE_OFF ((QKV_H_SIZE + VP_H_SIZE) * 2)  // byte offset of float region
#define GP_SIZE    (BATCH*8*32*48)                 // 98304 floats
#define M_SIZE     (BATCH*48*48)                   // 18432 floats
// float region: [gp][Mmat][w1t]

struct __align__(16) H8 { __half h[8]; };

// ===========================================================================
// K_t: transpose w1 (144x48) -> w1t (48x144): ka's weight reads become wide
// consecutive uniform s_loads.
// ===========================================================================
__global__ void kt_w1t(const float* __restrict__ w1, float* __restrict__ w1t)
{
  for (int i = threadIdx.x; i < 144 * 48; i += 256) {
    const int ic = i / 144, oc = i - ic * 144;
    w1t[i] = w1[oc * 48 + ic];
  }
}

// ===========================================================================
// K_a: 1x1 conv (48 -> 144), fp32 in, fp16 out. x tile (48x256 fp32 = 48 KB)
// staged in LDS so the compiler CANNOT re-load x from global per oc-chunk
// (the R2/R5 pathology). Inner loop: 1 ds_read_b32 + 16 FMA; weights are
// uniform s_loads from w1t. acc[16] -> ~40 VGPR, 3 blocks/CU (LDS-bound).
// ===========================================================================
__global__ __launch_bounds__(256, 4) void ka_conv1(
    const float* __restrict__ x, const float* __restrict__ w1t,
    __half* __restrict__ qkv)
{
  __shared__ float xs[48 * 256];
  const int tid = threadIdx.x;
  const int g0  = blockIdx.x * 256;
  const int b   = g0 >> 16;
  const int n0  = g0 & 65535;
  const float* xb = x + ((size_t)b * 48) * NPIX + n0;

  float4* xs4 = (float4*)xs;
#pragma unroll
  for (int j = 0; j < 12; ++j) {
    const int fi  = tid + j * 256;        // float4 index, 0..3071
    const int ic  = fi >> 6;              // 64 float4 per 256-px row
    const int off = (fi & 63) * 4;
    xs4[fi] = *(const float4*)(xb + (size_t)ic * NPIX + off);
  }
  __syncthreads();

  __half* ob = qkv + ((size_t)b * 144) * NPIX + n0 + tid;
#pragma unroll 1
  for (int c = 0; c < 9; ++c) {
    const int oc0 = c * 16;
    float acc[16];
#pragma unroll
    for (int j = 0; j < 16; ++j) acc[j] = 0.0f;
#pragma unroll 4
    for (int ic = 0; ic < 48; ++ic) {
      const float xr = xs[ic * 256 + tid];
      const float* wr = w1t + ic * 144 + oc0;
#pragma unroll
      for (int j = 0; j < 16; ++j) acc[j] = fmaf(wr[j], xr, acc[j]);
    }
#pragma unroll
    for (int j = 0; j < 16; ++j)
      ob[(size_t)(oc0 + j) * NPIX] = __float2half(acc[j]);
  }
}

// ===========================================================================
// K_b: merged streaming depthwise+gram+v. Block = (b, head, 8-row band);
// thread = 8 cols x 1 row (gcol=tid&31, rl=tid>>5). Per channel: 3 aligned
// H8 global loads (row overlap served by L1/L2), halo cols via shfl(width 32
// — row is uniform within each 32-lane group, so shfl is divergence-safe).
// 6 q-ch -> regs; 6 k-ch -> gram[48]; wave shfl-reduce gram EARLY (frees
// 48 VGPRs); then 6 v-ch -> fp16 H8 stores. LDS = 768 B only.
// ===========================================================================
__global__ __launch_bounds__(256, 3) void kb_dwgram(
    const __half* __restrict__ qkv, const float* __restrict__ wd,
    __half* __restrict__ vp_ws, float* __restrict__ gp)
{
  __shared__ float pr[4 * 48];
  const int blk  = blockIdx.x;             // b*256 + h*32 + band
  const int band = blk & 31;
  const int h    = (blk >> 5) & 7;
  const int b    = blk >> 8;
  const int tid  = threadIdx.x;
  const int gcol = tid & 31;
  const int rl   = tid >> 5;
  const int x0   = gcol * 8;
  const int y    = band * 8 + rl;
  const __half* qb = qkv + ((size_t)b * 144) * NPIX;

  auto loadrow = [&](const __half* plane, int yy, float f[10]) {
    if ((unsigned)yy < 256u) {
      const H8 m = *(const H8*)(plane + yy * 256 + x0);
      float t0 = __half2float(m.h[0]);
      float t7 = __half2float(m.h[7]);
      f[1] = t0;
#pragma unroll
      for (int q = 1; q < 7; ++q) f[q + 1] = __half2float(m.h[q]);
      f[8] = t7;
      const float fl = __shfl_up(t7, 1, 32);
      const float fr = __shfl_down(t0, 1, 32);
      f[0] = (gcol > 0)  ? fl : 0.0f;
      f[9] = (gcol < 31) ? fr : 0.0f;
    } else {
#pragma unroll
      for (int q = 0; q < 10; ++q) f[q] = 0.0f;
    }
  };

  auto dwc = [&](int gch, float o[8]) {
    const __half* plane = qb + (size_t)gch * NPIX;
    const float* w9 = wd + gch * 9;
    float f0[10], f1[10], f2[10];
    loadrow(plane, y - 1, f0);
    loadrow(plane, y,     f1);
    loadrow(plane, y + 1, f2);
#pragma unroll
    for (int p = 0; p < 8; ++p) {
      float s = 0.0f;
#pragma unroll
      for (int dx = 0; dx < 3; ++dx) {
        s = fmaf(w9[dx],     f0[p + dx], s);
        s = fmaf(w9[3 + dx], f1[p + dx], s);
        s = fmaf(w9[6 + dx], f2[p + dx], s);
      }
      o[p] = s;
    }
  };

  // ---- q channels ----
  float qv[6][8];
  float gram[48];
#pragma unroll
  for (int d = 0; d < 6; ++d) {
    dwc(6 * h + d, qv[d]);
    float s = 0.0f;
#pragma unroll
    for (int p = 0; p < 8; ++p) s = fmaf(qv[d][p], qv[d][p], s);
    gram[d] = s;
  }
  // ---- k channels + cross terms ----
#pragma unroll
  for (int e = 0; e < 6; ++e) {
    float kv[8];
    dwc(48 + 6 * h + e, kv);
    float s = 0.0f;
#pragma unroll
    for (int p = 0; p < 8; ++p) s = fmaf(kv[p], kv[p], s);
    gram[6 + e] = s;
#pragma unroll
    for (int d = 0; d < 6; ++d) {
      float t = 0.0f;
#pragma unroll
      for (int p = 0; p < 8; ++p) t = fmaf(qv[d][p], kv[p], t);
      gram[12 + 6 * d + e] = t;
    }
  }

  // ---- wave-level reduction NOW (frees gram's 48 VGPRs before v-phase) ----
  const int lane = tid & 63, wid = tid >> 6;
#pragma unroll
  for (int v = 0; v < 48; ++v) {
    float s = gram[v];
    s += __shfl_down(s, 32);
    s += __shfl_down(s, 16);
    s += __shfl_down(s, 8);
    s += __shfl_down(s, 4);
    s += __shfl_down(s, 2);
    s += __shfl_down(s, 1);
    gram[v] = s;
  }
  if (lane == 0) {
#pragma unroll
    for (int v = 0; v < 48; ++v) pr[wid * 48 + v] = gram[v];
  }

  // ---- v channels -> fp16 ----
#pragma unroll
  for (int j = 0; j < 6; ++j) {
    float o[8];
    dwc(96 + 6 * h + j, o);
    H8 hv;
#pragma unroll
    for (int p = 0; p < 8; ++p) hv.h[p] = __float2half(o[p]);
    *(H8*)(vp_ws + ((size_t)b * 48 + 6 * h + j) * NPIX + y * 256 + x0) = hv;
  }

  __syncthreads();
  if (tid < 48)
    gp[((size_t)((b * 8 + h) * 32) + band) * 48 + tid] =
        pr[tid] + pr[48 + tid] + pr[96 + tid] + pr[144 + tid];
}

// ===========================================================================
// K_d: per (b,head): sum 32 band partials -> norms -> softmax -> fold W_proj
// ===========================================================================
__global__ void kd_attn(const float* __restrict__ gp,
                        const float* __restrict__ wp, float* __restrict__ Mmat)
{
  const int b = blockIdx.x >> 3;
  const int h = blockIdx.x & 7;
  __shared__ float S[48];
  __shared__ float attn[36];
  const int tid = threadIdx.x;   // 64 threads

  if (tid < 48) {
    float s = 0.0f;
    for (int t = 0; t < 32; ++t)
      s += gp[((size_t)((b * 8 + h) * 32) + t) * 48 + tid];
    S[tid] = s;
  }
  __syncthreads();
  if (tid < 36) {
    const int d = tid / 6, e = tid - 6 * d;
    const float nq = fmaxf(sqrtf(S[d]),     1e-12f);
    const float nk = fmaxf(sqrtf(S[6 + e]), 1e-12f);
    attn[tid] = S[12 + tid] / (nq * nk) * SCALE;
  }
  __syncthreads();
  if (tid < 6) {
    float m = attn[tid * 6];
    for (int e = 1; e < 6; ++e) m = fmaxf(m, attn[tid * 6 + e]);
    float ex[6]; float sum = 0.0f;
    for (int e = 0; e < 6; ++e) { ex[e] = expf(attn[tid * 6 + e] - m); sum += ex[e]; }
    const float inv = 1.0f / sum;
    for (int e = 0; e < 6; ++e) attn[tid * 6 + e] = ex[e] * inv;
  }
  __syncthreads();
  for (int i = tid; i < 288; i += 64) {
    const int c = i / 6, e = i - 6 * (i / 6);
    float s = 0.0f;
#pragma unroll
    for (int d = 0; d < 6; ++d) s += wp[c * 48 + 6 * h + d] * attn[d * 6 + e];
    Mmat[((size_t)b * 48 + c) * 48 + 6 * h + e] = s;
  }
}

// ===========================================================================
// K_e: y[b][c][n] = sum_{c'} M_b[c][c'] * v'[b][c'][n]; 1 px/thread,
// vv[48] in VGPRs (spill-free at launch_bounds(256,4)).
// ===========================================================================
__global__ __launch_bounds__(256, 4) void ke_out(
    const __half* __restrict__ vp_ws, const float* __restrict__ Mmat,
    float* __restrict__ y)
{
  const int b = blockIdx.x >> 8;
  const int n = ((blockIdx.x & 255) << 8) + threadIdx.x;
  const __half* vb = vp_ws + ((size_t)b * 48) * NPIX + n;
  const float* Mb = Mmat + (size_t)b * 2304;
  float vv[48];
#pragma unroll
  for (int c = 0; c < 48; ++c) vv[c] = __half2float(vb[(size_t)c * NPIX]);
  float* yb = y + ((size_t)b * 48) * NPIX + n;
#pragma unroll 4
  for (int c = 0; c < 48; ++c) {
    float s = 0.0f;
#pragma unroll
    for (int cc = 0; cc < 48; ++cc) s = fmaf(Mb[c * 48 + cc], vv[cc], s);
    yb[(size_t)c * NPIX] = s;
  }
}

// ===========================================================================
extern "C" void kernel_launch(void* const* d_in, const int* in_sizes, int n_in,
                              void* d_out, int out_size, void* d_ws, size_t ws_size,
                              hipStream_t stream)
{
  const float* x  = (const float*)d_in[0];
  const float* w1 = (const float*)d_in[1];   // (144,48,1,1)
  const float* wd = (const float*)d_in[2];   // (144,1,3,3)
  const float* wp = (const float*)d_in[3];   // (48,48,1,1)

  __half* qkv = (__half*)d_ws;
  __half* vp  = qkv + QKV_H_SIZE;
  float*  fw  = (float*)((char*)d_ws + F_BYTE_OFF);
  float*  gp   = fw;
  float*  Mmat = fw + GP_SIZE;
  float*  w1t  = Mmat + M_SIZE;

  hipLaunchKernelGGL(kt_w1t,    dim3(1),    dim3(256), 0, stream, w1, w1t);
  hipLaunchKernelGGL(ka_conv1,  dim3(2048), dim3(256), 0, stream, x, w1t, qkv);
  hipLaunchKernelGGL(kb_dwgram, dim3(2048), dim3(256), 0, stream, qkv, wd, vp, gp);
  hipLaunchKernelGGL(kd_attn,   dim3(64),   dim3(64),  0, stream, gp, wp, Mmat);
  hipLaunchKernelGGL(ke_out,    dim3(2048), dim3(256), 0, stream, vp, Mmat, (float*)d_out);
}